// Round 6
// baseline (74.708 us; speedup 1.0000x reference)
//
#include <hip/hip_runtime.h>
#include <math.h>

// Problem constants (fixed by setup_inputs)
#define NL 4          // n_latents
#define MM 1024       // codebook entries per latent
#define DD 16         // dim per latent
#define PP 16384      // points = N*H*W
#define PLANE 1024    // H*W
#define NSTRIDE 65536 // z_dim*H*W
#define CHUNK 256     // points per workgroup (quarter plane)
#define NCHUNK (PP / CHUNK)   // 64
#define MGROUP 256    // codes per workgroup (4 waves x 2 strips x 32)
#define NMG (MM / MGROUP)     // 4
#define ZSTR 20       // LDS stride per point in f16 units (16 data + 4 pad = 40B)
#define SCR_STRIDE 33 // f32 words per row in the transpose-reduce scratch (conflict-free)
#define SCR_WAVE 1056 // 32*33 words per wave region
#define GRID (NL * NMG * NCHUNK)   // 1024 blocks
#define NRED 16                     // reduce blocks = NL*NMG
#define POISON_U32 0xAAAAAAAAu     // harness re-poisons ws with 0xAA bytes each launch

// Schraudolph-style fast 2^x: bitcast(u32(2^23*(x + B))), B = 127 - 0.0353
#define EXP2_SCALE 8388608.0f            // 2^23
#define EXP2_BIAS  126.9647f             // 127 - sigma*

typedef _Float16 half4v  __attribute__((ext_vector_type(4)));
typedef _Float16 half8v  __attribute__((ext_vector_type(8)));
typedef float    float16v __attribute__((ext_vector_type(16)));

// ============================== ROUND 6: ABLATION PROBE =====================
// Five rounds pin down: fill ~40.5 us (fixed harness cost), dist body ~25 us
// vs a ~7 us instruction model — a ~17 us mystery INSIDE dist, and dist's
// counters are invisible (top-5 rows are all 40-us fills). Blind structural
// bets (spills R0, node count R1/R4/R5, atomics R5) were all null.
// This round MEASURES instead of guessing: the exp-consume chain (96 VALU/
// iter, modeled 2.6 us) is TRIPLED via two dummy passes per strip whose
// results are kept alive by asm sinks (rule #17) with CSE defeated by
// asm-laundered azc copies. Real path is byte-identical -> absmax 0.0.
// Read: dur ~75 => consume at modeled rate (pig elsewhere: latency/stage).
//       dur >=85 => consume pipe degraded (cvt rate/issue) — consume is pig.
//       dur ~70 => consume fully latency-hidden — latency-bound kernel.
// ===========================================================================
//
// Structure (verified absmax=0 in R5): per (l, mg of 256 codes, chunk of 256
// points); each wave owns 2 strips of 32 codes.
//   dd[s] = (m2a2*e_strip_s)(32xK16) . z_tile(K16x32) + biasC[s]  (mfma 32x32x16 f16)
//   acc[s][r] += fast_exp2(dd[s][r] + a2*zsq[col])
// Epilogue: per-wave LDS transpose (stride 33), plain coalesced P stores
// (no atomics). Reduce kernel: 16 blocks + fence-free modulo counter gate.
// MFMA 32x32 C/D layout (HW-verified): col=lane&31, row=(reg&3)+8*(reg>>2)+4*(lane>>5)
__global__ __launch_bounds__(256, 4)
void latent_dist_kernel(const float* __restrict__ z, const float* __restrict__ e,
                        const float* __restrict__ log_sigma, float* __restrict__ P)
{
    const int t    = threadIdx.x;
    const int lane = t & 63;
    const int wave = t >> 6;
    const int ln31 = lane & 31;
    const int hf   = lane >> 5;

    const int bid = blockIdx.x;
    const int c   = bid & (NCHUNK - 1);       // p-chunk
    const int mg  = (bid >> 6) & (NMG - 1);   // m-group
    const int l   = bid >> 8;                 // latent

    const float ls    = log_sigma[0];
    const float alpha = -0.5f * __expf(-2.0f * ls);
    const float a2    = alpha * 1.44269504088896340736f; // alpha/ln2
    const float m2a2  = -2.0f * a2;

    __shared__ __attribute__((aligned(16))) char smem[4 * SCR_WAVE * 4];
    _Float16* zh  = (_Float16*)smem;
    float*    scr = (float*)smem;
    __shared__ float azqs[CHUNK];   // (a2*zsq + EXP2_BIAS) * 2^23  (magic form)
    __shared__ float esqs[MGROUP];

    // ---- Stage z chunk: one point per thread, 16 global f32 (coalesced) -> LDS f16.
    const int n  = c >> 2;
    const int q0 = (c & 3) * CHUNK;
    const float* zb = z + (size_t)n * NSTRIDE + (size_t)l * DD * PLANE + q0;

    float sq = 0.f;
#pragma unroll
    for (int dp = 0; dp < 8; ++dp) {
        float v0 = zb[(2 * dp)     * PLANE + t];
        float v1 = zb[(2 * dp + 1) * PLANE + t];
        sq += v0 * v0 + v1 * v1;
        union { _Float16 h[2]; unsigned u; } pk;
        pk.h[0] = (_Float16)v0; pk.h[1] = (_Float16)v1;
        *(unsigned*)(&zh[t * ZSTR + 2 * dp]) = pk.u;
    }
    azqs[t] = (sq * a2 + EXP2_BIAS) * EXP2_SCALE;

    // ---- A fragments for the wave's 2 strips (pre-scaled by m2a2) + exact f32 esq.
    const int m0 = mg * MGROUP + wave * 64;
    half8v Af[2];
#pragma unroll
    for (int s = 0; s < 2; ++s) {
        const float* eb = e + ((size_t)l * MM + m0 + s * 32 + ln31) * DD + hf * 8;
        float4 a0 = *(const float4*)eb;
        float4 a1 = *(const float4*)(eb + 4);
        float esq_p = a0.x*a0.x + a0.y*a0.y + a0.z*a0.z + a0.w*a0.w
                    + a1.x*a1.x + a1.y*a1.y + a1.z*a1.z + a1.w*a1.w;
        esq_p += __shfl_xor(esq_p, 32, 64);
        esqs[wave * 64 + s * 32 + ln31] = esq_p;
        Af[s][0] = (_Float16)(a0.x * m2a2); Af[s][1] = (_Float16)(a0.y * m2a2);
        Af[s][2] = (_Float16)(a0.z * m2a2); Af[s][3] = (_Float16)(a0.w * m2a2);
        Af[s][4] = (_Float16)(a1.x * m2a2); Af[s][5] = (_Float16)(a1.y * m2a2);
        Af[s][6] = (_Float16)(a1.z * m2a2); Af[s][7] = (_Float16)(a1.w * m2a2);
    }

    __syncthreads();

    float16v biasC[2];
#pragma unroll
    for (int s = 0; s < 2; ++s)
#pragma unroll
        for (int r = 0; r < 16; ++r) {
            const int row = (r & 3) + 8 * (r >> 2) + 4 * hf;
            biasC[s][r] = esqs[wave * 64 + s * 32 + row] * a2;
        }

    float16v acc[2];
#pragma unroll
    for (int s = 0; s < 2; ++s)
#pragma unroll
        for (int r = 0; r < 16; ++r) acc[s][r] = 0.f;

    const _Float16* zrow = zh + ln31 * ZSTR + hf * 8;

    float  az = azqs[ln31];
    half4v b0 = *(const half4v*)zrow;
    half4v b1 = *(const half4v*)(zrow + 4);

    // PROBE dummy accumulators (kept alive via asm sink below).
    float s2[4] = {0.f, 0.f, 0.f, 0.f};

#pragma unroll 1
    for (int pt = 0; pt < CHUNK / 32; ++pt) {
        half8v Bf = __builtin_shufflevector(b0, b1, 0, 1, 2, 3, 4, 5, 6, 7);
        const float azc = az;

        // Laundered copies of azc: formally distinct operands -> the dummy
        // fma/cvt chains cannot be CSE'd against the real pass.
        float azc2, azc3;
        asm("v_mov_b32 %0, %1" : "=v"(azc2) : "v"(azc));
        asm("v_mov_b32 %0, %1" : "=v"(azc3) : "v"(azc));

        const int nxt = (pt + 1) & (CHUNK / 32 - 1);
        const _Float16* bp = zrow + nxt * 32 * ZSTR;
        az = azqs[nxt * 32 + ln31];
        b0 = *(const half4v*)bp;
        b1 = *(const half4v*)(bp + 4);

        // ---- strip 0: real consume + 2 dummy consume passes (PROBE).
        float16v dd = __builtin_amdgcn_mfma_f32_32x32x16_f16(Af[0], Bf, biasC[0], 0, 0, 0);
#pragma unroll
        for (int r = 0; r < 16; ++r) {
            float u = fmaf(dd[r], EXP2_SCALE, azc);
            acc[0][r] += __uint_as_float(__float2uint_rz(u));
        }
#pragma unroll
        for (int r = 0; r < 16; ++r) {
            float u = fmaf(dd[r], EXP2_SCALE, azc2);
            s2[r & 3] += __uint_as_float(__float2uint_rz(u));
        }
#pragma unroll
        for (int r = 0; r < 16; ++r) {
            float u = fmaf(dd[r], EXP2_SCALE, azc3);
            s2[r & 3] += __uint_as_float(__float2uint_rz(u));
        }

        // ---- strip 1: real consume + 2 dummy consume passes (PROBE).
        dd = __builtin_amdgcn_mfma_f32_32x32x16_f16(Af[1], Bf, biasC[1], 0, 0, 0);
#pragma unroll
        for (int r = 0; r < 16; ++r) {
            float u = fmaf(dd[r], EXP2_SCALE, azc);
            acc[1][r] += __uint_as_float(__float2uint_rz(u));
        }
#pragma unroll
        for (int r = 0; r < 16; ++r) {
            float u = fmaf(dd[r], EXP2_SCALE, azc2);
            s2[r & 3] += __uint_as_float(__float2uint_rz(u));
        }
#pragma unroll
        for (int r = 0; r < 16; ++r) {
            float u = fmaf(dd[r], EXP2_SCALE, azc3);
            s2[r & 3] += __uint_as_float(__float2uint_rz(u));
        }
    }

    // Keep the dummy work observable at zero cost (guide rule #17).
    {
        float s2sum = (s2[0] + s2[1]) + (s2[2] + s2[3]);
        asm volatile("" :: "v"(s2sum));
    }

    // ---- Epilogue: per-wave transpose-reduce through LDS, one pass per strip.
    __syncthreads();
    float* scrw = scr + wave * SCR_WAVE;
    float* Prow = P + ((size_t)bid << 8);   // this block's private 256-float slice
#pragma unroll
    for (int s = 0; s < 2; ++s) {
#pragma unroll
        for (int r = 0; r < 16; ++r) {
            const int row = (r & 3) + 8 * (r >> 2) + 4 * hf;
            scrw[row * SCR_STRIDE + ln31] = acc[s][r];
        }
        const float* rp = scrw + ln31 * SCR_STRIDE + hf * 16;
        float sum = 0.f;
#pragma unroll
        for (int j = 0; j < 16; ++j) sum += rp[j];
        sum += __shfl_xor(sum, 32, 64);
        if (hf == 0)
            Prow[wave * 64 + s * 32 + ln31] = sum;   // PLAIN coalesced store
    }
}

// Reduce: 16 blocks, one per (l,mg). Fence-free counter gate (R4-verified).
__global__ __launch_bounds__(256)
void latent_reduce_kernel(const float* __restrict__ P,
                          const float* __restrict__ log_sigma,
                          float* __restrict__ P2, unsigned* __restrict__ counter,
                          float* __restrict__ out)
{
    const int b = blockIdx.x;     // (l,mg)
    const int t = threadIdx.x;    // code within mg
    __shared__ float red[4];
    __shared__ int   is_last;

    const float* base = P + ((size_t)b * NCHUNK << 8) + t;
    float s = 0.f;
#pragma unroll
    for (int c = 0; c < NCHUNK; ++c) s += base[c << 8];
    float lg = __logf(s);
#pragma unroll
    for (int off = 32; off > 0; off >>= 1) lg += __shfl_down(lg, off, 64);
    if ((t & 63) == 0) red[t >> 6] = lg;
    __syncthreads();
    if (t == 0) {
        __hip_atomic_store(&P2[b], red[0] + red[1] + red[2] + red[3],
                           __ATOMIC_RELAXED, __HIP_MEMORY_SCOPE_AGENT);
    }
    __syncthreads();  // drains vmcnt: P2 store completed before counter bump
    if (t == 0) {
        unsigned old = __hip_atomic_fetch_add(counter, 1u, __ATOMIC_RELAXED,
                                              __HIP_MEMORY_SCOPE_AGENT);
        is_last = (((old - POISON_U32 + 1u) & (unsigned)(NRED - 1)) == 0u);
    }
    __syncthreads();
    if (!is_last || t != 0) return;

    float tot = 0.f;
#pragma unroll
    for (int i = 0; i < NRED; ++i)
        tot += __hip_atomic_load(&P2[i], __ATOMIC_RELAXED, __HIP_MEMORY_SCOPE_AGENT);
    const float ls = log_sigma[0];
    out[0] = -tot / (float)(NL * MM)
           + 32.0f * (2.0f * ls - 1.0f)   // 0.5*z_dim*(2ls-1), z_dim=64
           + 9.70406052783923f;           // ln(16384)
}

extern "C" void kernel_launch(void* const* d_in, const int* in_sizes, int n_in,
                              void* d_out, int out_size, void* d_ws, size_t ws_size,
                              hipStream_t stream)
{
    const float* z  = (const float*)d_in[0];
    const float* e  = (const float*)d_in[1];
    const float* ls = (const float*)d_in[2];
    float* out = (float*)d_out;
    float* P   = (float*)d_ws;                       // 1 MB partials, fully overwritten
    float* P2  = (float*)((char*)d_ws + (size_t)GRID * 256 * sizeof(float)); // 16 floats
    unsigned* counter = (unsigned*)((char*)P2 + 64); // gate counter (poison-start ok)

    latent_dist_kernel<<<GRID, 256, 0, stream>>>(z, e, ls, P);
    latent_reduce_kernel<<<NRED, 256, 0, stream>>>(P, ls, P2, counter, out);
}